// Round 1
// baseline (231.904 us; speedup 1.0000x reference)
//
#include <hip/hip_runtime.h>
#include <hip/hip_bf16.h>

#define N_PIX 8192
#define C_DIM 128
#define HW 4096
// 1/TEMPERATURE * log2(e) : exp(x/0.1) = exp2(x * 14.42695...)
#define SCALE_LOG2 14.426950408889634f
#define NUM_CLASSES 4

typedef __attribute__((ext_vector_type(8))) short short8;   // 8 x bf16 (4 VGPRs)
typedef __attribute__((ext_vector_type(4))) float float4v;  // 4 x f32 acc

// ---------------- Kernel 1: L2-normalize rows, cast to bf16, layout [N][C] ----------------
__global__ __launch_bounds__(256) void normalize_kernel(const float* __restrict__ emb,
                                                        unsigned short* __restrict__ ebf) {
    int n = blockIdx.x * blockDim.x + threadIdx.x;  // pixel index 0..8191
    int b = n >> 12;
    int hw = n & (HW - 1);
    const float* base = emb + b * (C_DIM * HW) + hw;
    float ss = 0.f;
#pragma unroll 8
    for (int c = 0; c < C_DIM; ++c) {
        float v = base[c * HW];
        ss += v * v;
    }
    float inv = 1.0f / fmaxf(sqrtf(ss), 1e-12f);
    unsigned short* dst = ebf + n * C_DIM;
#pragma unroll 8
    for (int c = 0; c < C_DIM; ++c) {
        float v = base[c * HW] * inv;
        __hip_bfloat16 h = __float2bfloat16(v);
        dst[c] = *reinterpret_cast<unsigned short*>(&h);
    }
}

// ---------------- Kernel 2: fused S = e e^T / T, exp, masked row sums ----------------
// Grid: (128 row-tiles of 64, 4 j-splits of 2048). Block: 256 threads = 4 waves.
// Wave w handles rows [bx*64 + w*16, +16), loops j in chunks of 64 (4 tiles of 16).
__global__ __launch_bounds__(256) void pairwise_kernel(const unsigned short* __restrict__ ebf,
                                                       const int* __restrict__ lab,
                                                       float* __restrict__ pos,
                                                       float* __restrict__ tot) {
    const int wave = threadIdx.x >> 6;
    const int lane = threadIdx.x & 63;
    const int quad = lane >> 4;   // 0..3
    const int lq = lane & 15;     // 0..15

    const int I0 = blockIdx.x * 64 + wave * 16;
    const int Jbase0 = blockIdx.y * 2048;

    // A fragments: A[m=lq][k = s*32 + quad*8 + j], rows I0..I0+15, loaded once.
    short8 afrag[4];
    {
        const unsigned short* arow = ebf + (I0 + lq) * C_DIM + quad * 8;
#pragma unroll
        for (int s = 0; s < 4; ++s)
            afrag[s] = *reinterpret_cast<const short8*>(arow + s * 32);
    }
    int lab_row[4];
#pragma unroll
    for (int r = 0; r < 4; ++r) lab_row[r] = lab[I0 + quad * 4 + r];

    float tot_acc[4] = {0.f, 0.f, 0.f, 0.f};
    float pos_acc[4] = {0.f, 0.f, 0.f, 0.f};

    for (int jc = 0; jc < 32; ++jc) {
        const int Jb = Jbase0 + jc * 64;
#pragma unroll
        for (int jt = 0; jt < 4; ++jt) {
            const int J = Jb + jt * 16;
            const unsigned short* brow = ebf + (J + lq) * C_DIM + quad * 8;
            float4v acc = {0.f, 0.f, 0.f, 0.f};
#pragma unroll
            for (int s = 0; s < 4; ++s) {
                short8 bfrag = *reinterpret_cast<const short8*>(brow + s * 32);
                acc = __builtin_amdgcn_mfma_f32_16x16x32_bf16(afrag[s], bfrag, acc, 0, 0, 0);
            }
            // C/D layout: col = lane&15 (within tile), row = quad*4 + reg
            const int col = J + lq;
            const int lab_col = lab[col];
#pragma unroll
            for (int r = 0; r < 4; ++r) {
                const int row = I0 + quad * 4 + r;
                float ex = __builtin_amdgcn_exp2f(acc[r] * SCALE_LOG2);
                ex = (row == col) ? 0.f : ex;  // diagonal mask (exp(-1e10) == 0)
                tot_acc[r] += ex;
                pos_acc[r] += (lab_row[r] == lab_col) ? ex : 0.f;
            }
        }
    }

    // Reduce across the 16 lanes of each quad-group (they share rows, differ in col%16)
#pragma unroll
    for (int r = 0; r < 4; ++r) {
        float t = tot_acc[r], p = pos_acc[r];
#pragma unroll
        for (int off = 1; off < 16; off <<= 1) {
            t += __shfl_xor(t, off, 64);
            p += __shfl_xor(p, off, 64);
        }
        if (lq == 0) {
            const int row = I0 + quad * 4 + r;
            atomicAdd(&tot[row], t);
            atomicAdd(&pos[row], p);
        }
    }
}

// ---------------- Kernel 3: row losses + per-class mean of means ----------------
__global__ __launch_bounds__(256) void finalize_kernel(const float* __restrict__ pos,
                                                       const float* __restrict__ tot,
                                                       const int* __restrict__ lab,
                                                       float* __restrict__ out) {
    __shared__ float s_sum[NUM_CLASSES];
    __shared__ int s_cnt[NUM_CLASSES];
    const int tid = threadIdx.x;
    if (tid < NUM_CLASSES) {
        s_sum[tid] = 0.f;
        s_cnt[tid] = 0;
    }
    __syncthreads();
    float lsum[NUM_CLASSES] = {0.f, 0.f, 0.f, 0.f};
    int lcnt[NUM_CLASSES] = {0, 0, 0, 0};
    for (int n = tid; n < N_PIX; n += 256) {
        // -log(pos/(tot+eps)) = log(tot+eps) - log(pos)
        float rl = logf(tot[n] + 1e-6f) - logf(pos[n]);
        int c = lab[n];
#pragma unroll
        for (int k = 0; k < NUM_CLASSES; ++k) {
            if (c == k) {
                lsum[k] += rl;
                lcnt[k]++;
            }
        }
    }
#pragma unroll
    for (int k = 0; k < NUM_CLASSES; ++k) {
        atomicAdd(&s_sum[k], lsum[k]);
        atomicAdd(&s_cnt[k], lcnt[k]);
    }
    __syncthreads();
    if (tid == 0) {
        float acc = 0.f;
        int present = 0;
        for (int k = 0; k < NUM_CLASSES; ++k) {
            if (s_cnt[k] > 0) {
                acc += s_sum[k] / (float)s_cnt[k];
                present++;
            }
        }
        out[0] = acc / (float)(present > 0 ? present : 1);
    }
}

extern "C" void kernel_launch(void* const* d_in, const int* in_sizes, int n_in,
                              void* d_out, int out_size, void* d_ws, size_t ws_size,
                              hipStream_t stream) {
    const float* emb = (const float*)d_in[0];  // [2,128,64,64] fp32
    const int* lab = (const int*)d_in[1];      // [2,64,64] int32, flat == pixel order
    float* out = (float*)d_out;

    unsigned short* ebf = (unsigned short*)d_ws;                    // [8192][128] bf16 = 2 MiB
    float* pos = (float*)((char*)d_ws + N_PIX * C_DIM * 2);         // [8192] f32
    float* tot = pos + N_PIX;                                       // [8192] f32

    hipMemsetAsync(pos, 0, 2 * N_PIX * sizeof(float), stream);

    normalize_kernel<<<N_PIX / 256, 256, 0, stream>>>(emb, ebf);

    dim3 grid(N_PIX / 64, 4);  // 128 row-tiles x 4 j-splits = 512 blocks
    pairwise_kernel<<<grid, 256, 0, stream>>>(ebf, lab, pos, tot);

    finalize_kernel<<<1, 256, 0, stream>>>(pos, tot, lab, out);
}

// Round 2
// 151.856 us; speedup vs baseline: 1.5271x; 1.5271x over previous
//
#include <hip/hip_runtime.h>
#include <hip/hip_bf16.h>

#define N_PIX 8192
#define C_DIM 128
#define HW 4096
// 1/TEMPERATURE * log2(e) : exp(x/0.1) = exp2(x * 14.42695...)
#define SCALE_LOG2 14.426950408889634f
#define NUM_CLASSES 4

typedef __attribute__((ext_vector_type(8))) short short8;   // 8 x bf16 (4 VGPRs)
typedef __attribute__((ext_vector_type(4))) float float4v;  // 4 x f32 acc

// ---------------- Kernel 1: L2-normalize rows, cast to bf16, layout [N][C] ----------------
// 4 threads per pixel (one 32-channel group each); 64 pixels per 256-thread block.
__global__ __launch_bounds__(256) void normalize_kernel(const float* __restrict__ emb,
                                                        unsigned short* __restrict__ ebf) {
    const int p = threadIdx.x & 63;   // pixel within block (lane)
    const int q = threadIdx.x >> 6;   // channel group 0..3 (wave id)
    const int n = blockIdx.x * 64 + p;
    const int b = n >> 12;
    const int hw = n & (HW - 1);
    const float* base = emb + b * (C_DIM * HW) + hw;

    float v[32];
    float ss = 0.f;
#pragma unroll
    for (int i = 0; i < 32; ++i) {
        v[i] = base[(q * 32 + i) * HW];
        ss += v[i] * v[i];
    }
    __shared__ float red[4][64];
    red[q][p] = ss;
    __syncthreads();
    float tot = red[0][p] + red[1][p] + red[2][p] + red[3][p];
    float inv = 1.0f / fmaxf(sqrtf(tot), 1e-12f);

    unsigned short us[32];
#pragma unroll
    for (int i = 0; i < 32; ++i) {
        __hip_bfloat16 h = __float2bfloat16(v[i] * inv);
        us[i] = *reinterpret_cast<unsigned short*>(&h);
    }
    unsigned short* dst = ebf + n * C_DIM + q * 32;
#pragma unroll
    for (int s = 0; s < 4; ++s)
        *reinterpret_cast<short8*>(dst + s * 8) = *reinterpret_cast<short8*>(us + s * 8);
}

// ---------------- Kernel 2: fused S = e e^T / T, exp, masked row sums ----------------
// Grid: (64 row-blocks of 128 rows, 16 j-splits of 512 cols). Block: 256 = 4 waves.
// Wave w holds 2 A-sets (32 rows) in registers; each B fragment feeds 8 MFMAs.
__global__ __launch_bounds__(256, 4) void pairwise_kernel(const unsigned short* __restrict__ ebf,
                                                          const int* __restrict__ lab,
                                                          float* __restrict__ pos,
                                                          float* __restrict__ tot) {
    const int wave = threadIdx.x >> 6;
    const int lane = threadIdx.x & 63;
    const int quad = lane >> 4;   // 0..3
    const int lq = lane & 15;     // 0..15

    const int I0 = blockIdx.x * 128 + wave * 32;   // first of this wave's 32 rows
    const int Jbase = blockIdx.y * 512;            // this block's 512-col chunk

    // A fragments: A[m=lq][k = s*32 + quad*8 + j] for 2 row-sets, loaded once.
    short8 afrag[2][4];
#pragma unroll
    for (int a = 0; a < 2; ++a) {
        const unsigned short* arow = ebf + (I0 + a * 16 + lq) * C_DIM + quad * 8;
#pragma unroll
        for (int s = 0; s < 4; ++s)
            afrag[a][s] = *reinterpret_cast<const short8*>(arow + s * 32);
    }
    int lab_row[2][4];
#pragma unroll
    for (int a = 0; a < 2; ++a)
#pragma unroll
        for (int r = 0; r < 4; ++r) lab_row[a][r] = lab[I0 + a * 16 + quad * 4 + r];

    float tacc[2][4] = {};
    float pacc[2][4] = {};

    for (int jt = 0; jt < 32; ++jt) {
        const int J = Jbase + jt * 16;
        const int col = J + lq;
        const int lab_col = lab[col];  // issue early; 16 distinct 4B, L1-resident
        const unsigned short* brow = ebf + (J + lq) * C_DIM + quad * 8;
        short8 bfrag[4];
#pragma unroll
        for (int s = 0; s < 4; ++s)
            bfrag[s] = *reinterpret_cast<const short8*>(brow + s * 32);

        float4v acc[2];
        acc[0] = float4v{0.f, 0.f, 0.f, 0.f};
        acc[1] = float4v{0.f, 0.f, 0.f, 0.f};
#pragma unroll
        for (int s = 0; s < 4; ++s) {
            acc[0] = __builtin_amdgcn_mfma_f32_16x16x32_bf16(afrag[0][s], bfrag[s], acc[0], 0, 0, 0);
            acc[1] = __builtin_amdgcn_mfma_f32_16x16x32_bf16(afrag[1][s], bfrag[s], acc[1], 0, 0, 0);
        }
        // C/D layout: col = lane&15 (within tile), row = quad*4 + reg
#pragma unroll
        for (int a = 0; a < 2; ++a) {
#pragma unroll
            for (int r = 0; r < 4; ++r) {
                const int row = I0 + a * 16 + quad * 4 + r;
                float ex = __builtin_amdgcn_exp2f(acc[a][r] * SCALE_LOG2);
                ex = (row == col) ? 0.f : ex;  // diagonal mask
                tacc[a][r] += ex;
                pacc[a][r] += (lab_row[a][r] == lab_col) ? ex : 0.f;
            }
        }
    }

    // Reduce across the 16 lanes of each quad-group, then one atomic per row-reg.
#pragma unroll
    for (int a = 0; a < 2; ++a) {
#pragma unroll
        for (int r = 0; r < 4; ++r) {
            float t = tacc[a][r], p = pacc[a][r];
#pragma unroll
            for (int off = 1; off < 16; off <<= 1) {
                t += __shfl_xor(t, off, 64);
                p += __shfl_xor(p, off, 64);
            }
            if (lq == 0) {
                const int row = I0 + a * 16 + quad * 4 + r;
                atomicAdd(&tot[row], t);
                atomicAdd(&pos[row], p);
            }
        }
    }
}

// ---------------- Kernel 3: row losses + per-class mean of means ----------------
__global__ __launch_bounds__(1024) void finalize_kernel(const float* __restrict__ pos,
                                                        const float* __restrict__ tot,
                                                        const int* __restrict__ lab,
                                                        float* __restrict__ out) {
    __shared__ float s_sum[NUM_CLASSES];
    __shared__ int s_cnt[NUM_CLASSES];
    const int tid = threadIdx.x;
    if (tid < NUM_CLASSES) {
        s_sum[tid] = 0.f;
        s_cnt[tid] = 0;
    }
    __syncthreads();
    float lsum[NUM_CLASSES] = {0.f, 0.f, 0.f, 0.f};
    int lcnt[NUM_CLASSES] = {0, 0, 0, 0};
    for (int n = tid; n < N_PIX; n += 1024) {
        float rl = logf(tot[n] + 1e-6f) - logf(pos[n]);
        int c = lab[n];
#pragma unroll
        for (int k = 0; k < NUM_CLASSES; ++k) {
            if (c == k) {
                lsum[k] += rl;
                lcnt[k]++;
            }
        }
    }
#pragma unroll
    for (int k = 0; k < NUM_CLASSES; ++k) {
        atomicAdd(&s_sum[k], lsum[k]);
        atomicAdd(&s_cnt[k], lcnt[k]);
    }
    __syncthreads();
    if (tid == 0) {
        float acc = 0.f;
        int present = 0;
        for (int k = 0; k < NUM_CLASSES; ++k) {
            if (s_cnt[k] > 0) {
                acc += s_sum[k] / (float)s_cnt[k];
                present++;
            }
        }
        out[0] = acc / (float)(present > 0 ? present : 1);
    }
}

extern "C" void kernel_launch(void* const* d_in, const int* in_sizes, int n_in,
                              void* d_out, int out_size, void* d_ws, size_t ws_size,
                              hipStream_t stream) {
    const float* emb = (const float*)d_in[0];  // [2,128,64,64] fp32
    const int* lab = (const int*)d_in[1];      // [2,64,64] int32
    float* out = (float*)d_out;

    unsigned short* ebf = (unsigned short*)d_ws;             // [8192][128] bf16 = 2 MiB
    float* pos = (float*)((char*)d_ws + N_PIX * C_DIM * 2);  // [8192] f32
    float* tot = pos + N_PIX;                                // [8192] f32

    hipMemsetAsync(pos, 0, 2 * N_PIX * sizeof(float), stream);

    normalize_kernel<<<N_PIX / 64, 256, 0, stream>>>(emb, ebf);

    dim3 grid(N_PIX / 128, 16);  // 64 row-blocks x 16 j-splits = 1024 blocks
    pairwise_kernel<<<grid, 256, 0, stream>>>(ebf, lab, pos, tot);

    finalize_kernel<<<1, 1024, 0, stream>>>(pos, tot, lab, out);
}